// Round 4
// baseline (18847.350 us; speedup 1.0000x reference)
//
#include <hip/hip_runtime.h>
#include <hip/hip_bf16.h>

// Problem constants
#define B_   32
#define S_   2048
#define I_   256
#define H_   256
#define TC   16      // timesteps per precompute WG

typedef __attribute__((ext_vector_type(8))) short short8;   // 8 x bf16 MFMA frag
typedef __attribute__((ext_vector_type(4))) float f32x4;
typedef unsigned long long u64;

__device__ __forceinline__ unsigned short f2bf(float f) {
  unsigned u = __builtin_bit_cast(unsigned, f);
  return (unsigned short)((u + 0x7FFFu + ((u >> 16) & 1u)) >> 16);  // RNE
}
__device__ __forceinline__ float bf2f(unsigned short b) {
  unsigned u = ((unsigned)b) << 16;
  return __builtin_bit_cast(float, u);
}
__device__ __forceinline__ float fast_rcp(float x) { return __builtin_amdgcn_rcpf(x); }
// |inputs| are bounded (<~8) in this net: no overflow concerns.
__device__ __forceinline__ float fast_tanh(float x) {
  return 1.f - 2.f * fast_rcp(__expf(2.f * x) + 1.f);
}
__device__ __forceinline__ float fast_sig(float x) {
  return fast_rcp(1.f + __expf(-x));
}
// Pack 2 hidden units into one exchange word: low dword = (hi0|hi1<<16),
// high dword = (lo0|lo1<<16) with tag in lo0's LSB.
__device__ __forceinline__ u64 packw(float v0, float v1, unsigned tagw) {
  unsigned short h0h = f2bf(v0);
  unsigned short h0l = f2bf(v0 - bf2f(h0h));
  unsigned short h1h = f2bf(v1);
  unsigned short h1l = f2bf(v1 - bf2f(h1h));
  unsigned hiw = (unsigned)h0h | ((unsigned)h1h << 16);
  unsigned low = (((unsigned)h0l & 0xFFFEu) | tagw) | ((unsigned)h1l << 16);
  return (u64)hiw | ((u64)low << 32);
}

// ===================== 2-wave/SIMD wave-autonomous path =====================
// 16 WGs x 512 threads = 128 waves on 16 CUs (2 waves/SIMD, 145KB LDS -> 1 WG/CU).
// Role of wave (wv in WG): group g = wv>>2 (batches [g*16,g*16+16), M=16 full
// MFMA tile), ug4 = blockIdx*4 + (wv&3) (units [ug4*4,ug4*4+4) x 4 gates =
// one N=16 tile via col(mm) = (mm>>2)*256 + ug4*4 + (mm&3)). Waves wv and
// wv+4 share a SIMD and carry OPPOSITE groups: the groups are independent
// recurrence chains, so one group's exchange round trip hides under the
// other's compute. Wave-private LDS, zero barriers, 24 MFMA/wave/step.
//
// Exchange (u64): idx = parity*4096 + g*2048 + b*128 + up
//   (parity = t&1, b = batch-in-group 0..15, up = unit pair 0..127).
// Validity: tag bit (lo0 LSB) == (t>>1)&1. 2-buffer overwrite safety: a
// producer publishes h(t+2) only after consuming all of h(t+1), whose
// producers consumed all of h(t) first -> no consumer still needs h(t).

__global__ void pack_h0_v(const float* __restrict__ h0, u64* __restrict__ hex) {
  int idx = blockIdx.x * 256 + threadIdx.x;   // 0..4095 = g*2048 + b*128 + up
  int up = idx & 127;
  int b  = (idx >> 7) & 15;
  int g  = idx >> 11;
  const float* hp = h0 + ((g * 16 + b) * 256 + up * 2);
  hex[idx] = packw(hp[0], hp[1], 0u);   // tag(t=0) = 0
}

// zx = x@Wx + bias in the consumer's per-(t,g,ug4) tile layout:
// element (t, g, ug4, col mm, row r4) at ((t*2+g)*64+ug4)*256 + mm*16 + r4
// (col-major within tile so lane (q,mm) reads one f32x4).  256 MiB total.
__global__ __launch_bounds__(256) void zx_precompute_v(
    const float* __restrict__ x, const float* __restrict__ W,
    const float* __restrict__ bias, float* __restrict__ zx) {
  __shared__ unsigned short xlds[16 * 264];

  const int tid  = threadIdx.x;
  const int bsub = blockIdx.x & 31;
  const int tc   = blockIdx.x >> 5;
  const int g    = bsub >> 4;
  const int ugq  = bsub & 15;
  const int lane = tid & 63;
  const int wv   = tid >> 6;
  const int ug4  = ugq * 4 + wv;
  const int q    = lane >> 4;
  const int mm   = lane & 15;

  short8 wx[8];
  const int col = (mm >> 2) * 256 + ug4 * 4 + (mm & 3);
  const float bia = bias[col];
  #pragma unroll
  for (int kc = 0; kc < 8; ++kc) {
    short8 v;
    #pragma unroll
    for (int j = 0; j < 8; ++j)
      v[j] = (short)f2bf(W[(long)(kc * 32 + q * 8 + j) * 1024 + col]);
    wx[kc] = v;
  }

  for (int tt = 0; tt < TC; ++tt) {
    const int t = tc * TC + tt;
    // stage x_t for this group's 16 batches as bf16
    const int xb = tid >> 4, xc0 = (tid & 15) * 16;
    const float* xp = x + ((long)(g * 16 + xb) * S_ + t) * I_ + xc0;
    unsigned short u16[16];
    #pragma unroll
    for (int k2 = 0; k2 < 4; ++k2) {
      f32x4 a = *(const f32x4*)(xp + k2 * 4);
      #pragma unroll
      for (int j = 0; j < 4; ++j) u16[k2 * 4 + j] = f2bf(a[j]);
    }
    *(uint4*)&xlds[xb * 264 + xc0]     = *(const uint4*)&u16[0];
    *(uint4*)&xlds[xb * 264 + xc0 + 8] = *(const uint4*)&u16[8];
    __syncthreads();
    f32x4 acc = {0.f, 0.f, 0.f, 0.f};
    #pragma unroll
    for (int kc = 0; kc < 8; ++kc) {
      short8 a = *(const short8*)&xlds[mm * 264 + kc * 32 + q * 8];
      acc = __builtin_amdgcn_mfma_f32_16x16x32_bf16(a, wx[kc], acc, 0, 0, 0);
    }
    f32x4 s;
    #pragma unroll
    for (int r = 0; r < 4; ++r) s[r] = acc[r] + bia;
    *(f32x4*)(zx + ((long)(t * 2 + g) * 64 + ug4) * 256 + mm * 16 + q * 4) = s;
    __syncthreads();   // protect xlds before next stage
  }
}

__global__ __launch_bounds__(512, 2) void lstm_wave2(
    const float* __restrict__ c0, float* __restrict__ out,
    u64* __restrict__ hex, const float* __restrict__ W,
    const float* __restrict__ zx) {
  // dynamic LDS, all regions strictly wave-private:
  // [wv*16896, +8448) hi plane, [+8448, +16896) lo plane (16 rows x 264 shorts)
  // [135168 + wv*1280, +1280) zb (16 rows x 20 floats)
  extern __shared__ char smem[];

  const int tid  = threadIdx.x;
  const int wv   = tid >> 6;
  const int lane = tid & 63;
  const int g    = wv >> 2;                 // batch group 0/1
  const int ug4  = blockIdx.x * 4 + (wv & 3);
  const int q    = lane >> 4;
  const int mm   = lane & 15;

  unsigned short* const hh = (unsigned short*)(smem + wv * 16896);
  unsigned short* const hl = hh + 4224;
  float* const zb = (float*)(smem + 135168 + wv * 1280);

  // ---- one-time: Wh fragments (hi/lo bf16) for this wave's 16 cols
  short8 whh[8], whl[8];
  const int col = (mm >> 2) * 256 + ug4 * 4 + (mm & 3);
  #pragma unroll
  for (int kc = 0; kc < 8; ++kc) {
    short8 vh, vl;
    #pragma unroll
    for (int j = 0; j < 8; ++j) {
      int k = kc * 32 + q * 8 + j;
      float w = W[(long)(256 + k) * 1024 + col];
      unsigned short hi = f2bf(w);
      vh[j] = (short)hi;
      vl[j] = (short)f2bf(w - bf2f(hi));
    }
    whh[kc] = vh; whl[kc] = vl;
  }

  // combine: lane owns (batch-in-group cb, unit offset uo)
  const int cb = lane >> 2;
  const int uo = lane & 3;
  const int u  = ug4 * 4 + uo;
  const int bg = g * 16 + cb;               // global batch
  float cs = c0[bg * 256 + u];

  // pre-blast t=0 words (parity 0, seeded by pack_h0_v; stream-ordered)
  u64 hv[32];
  {
    u64* bsrc = hex + g * 2048;
    #pragma unroll
    for (int j = 0; j < 32; ++j)
      hv[j] = __hip_atomic_load(bsrc + (j >> 1) * 128 + lane * 2 + (j & 1),
                                __ATOMIC_RELAXED, __HIP_MEMORY_SCOPE_AGENT);
  }
  f32x4 zxv = *(const f32x4*)(zx + ((long)g * 64 + ug4) * 256 + mm * 16 + q * 4);

  // de-phase group 1 by ~1 ktick so the two groups' spin windows anti-align
  // on their shared SIMDs (groups are independent chains; offset persists)
  if (g == 1) { __builtin_amdgcn_s_sleep(15); }

  for (int t = 0; t < S_; ++t) {
    const unsigned tagbit = (unsigned)((t >> 1) & 1);

    // 1. tag-check pre-blasted words; retry only stale ones (wave-local)
    unsigned need = 0;
    #pragma unroll
    for (int j = 0; j < 32; ++j)
      if ((((unsigned)(hv[j] >> 32)) & 1u) != tagbit) need |= 1u << j;
    if (__ballot(need != 0u) != 0ull) {
      u64* hsrc = hex + (t & 1) * 4096 + g * 2048;
      do {
        #pragma unroll
        for (int j = 0; j < 32; ++j)
          if (need & (1u << j))
            hv[j] = __hip_atomic_load(hsrc + (j >> 1) * 128 + lane * 2 + (j & 1),
                                      __ATOMIC_RELAXED, __HIP_MEMORY_SCOPE_AGENT);
        unsigned n2 = 0;
        #pragma unroll
        for (int j = 0; j < 32; ++j)
          if ((need & (1u << j)) && ((((unsigned)(hv[j] >> 32)) & 1u) != tagbit))
            n2 |= 1u << j;
        need = n2;
      } while (__ballot(need != 0u) != 0ull);
    }

    // 2. stage hi/lo planes (wave-private; lane covers units 4l..4l+3)
    #pragma unroll
    for (int j = 0; j < 32; ++j) {
      int b = j >> 1, s = j & 1;
      *(unsigned*)&hh[b * 264 + lane * 4 + s * 2] = (unsigned)hv[j];
      *(unsigned*)&hl[b * 264 + lane * 4 + s * 2] = (unsigned)(hv[j] >> 32);
    }
    asm volatile("s_waitcnt lgkmcnt(0)" ::: "memory");
    __builtin_amdgcn_sched_barrier(0);

    // 3. MFMA: M=16 (full tile), N=16, K=256; accH + accM (hi*lo + lo*hi)
    f32x4 aH = {0.f, 0.f, 0.f, 0.f}, aM = {0.f, 0.f, 0.f, 0.f};
    #pragma unroll
    for (int kc = 0; kc < 8; ++kc) {
      short8 ahh = *(const short8*)&hh[mm * 264 + kc * 32 + q * 8];
      short8 ahl = *(const short8*)&hl[mm * 264 + kc * 32 + q * 8];
      aH = __builtin_amdgcn_mfma_f32_16x16x32_bf16(ahh, whh[kc], aH, 0, 0, 0);
      aM = __builtin_amdgcn_mfma_f32_16x16x32_bf16(ahh, whl[kc], aM, 0, 0, 0);
      aM = __builtin_amdgcn_mfma_f32_16x16x32_bf16(ahl, whh[kc], aM, 0, 0, 0);
    }

    // 4. z = tanh(zx + h@Wh) -> zb; then zx reload for t+1 (in flight a step)
    #pragma unroll
    for (int r = 0; r < 4; ++r)
      zb[(q * 4 + r) * 20 + mm] = fast_tanh(aH[r] + aM[r] + zxv[r]);
    {
      int tn = (t + 1 < S_) ? (t + 1) : t;
      zxv = *(const f32x4*)(zx + ((long)(tn * 2 + g) * 64 + ug4) * 256 +
                            mm * 16 + q * 4);
    }
    asm volatile("s_waitcnt lgkmcnt(0)" ::: "memory");
    __builtin_amdgcn_sched_barrier(0);

    // 5. combine (wave-local: this wave owns all 4 gates of its units)
    float zi = zb[cb * 20 +  0 + uo];
    float zf = zb[cb * 20 +  4 + uo];
    float zg = zb[cb * 20 +  8 + uo];
    float zo = zb[cb * 20 + 12 + uo];
    float ig = fast_sig(zi);
    float fg = fast_sig(zf);
    float gg = fast_tanh(zg);
    float og = fast_sig(zo);
    float cn = fg * cs + ig * gg;
    cs = cn;
    float hn = fast_tanh(cn) * og;

    // 6. publish tagged word first (critical path), then out store
    float hp = __shfl_xor(hn, 1);
    if ((lane & 1) == 0) {
      u64 word = packw(hn, hp, (unsigned)(((t + 1) >> 1) & 1));
      __hip_atomic_store(hex + ((t + 1) & 1) * 4096 + g * 2048 + cb * 128 +
                             ug4 * 2 + (uo >> 1),
                         word, __ATOMIC_RELAXED, __HIP_MEMORY_SCOPE_AGENT);
    }
    out[((long)bg * S_ + t) * H_ + u] = hn;

    // 7. blast next parity (latency + late producers covered by partner wave
    //    on this SIMD computing the other group; tag-retry is the backstop)
    {
      u64* bsrc = hex + ((t + 1) & 1) * 4096 + g * 2048;
      #pragma unroll
      for (int j = 0; j < 32; ++j)
        hv[j] = __hip_atomic_load(bsrc + (j >> 1) * 128 + lane * 2 + (j & 1),
                                  __ATOMIC_RELAXED, __HIP_MEMORY_SCOPE_AGENT);
    }
  }
}

// ===================== legacy fallback (small-workspace) path =====================

__global__ void pack_h0_kernel(const float* __restrict__ h0, u64* __restrict__ hex) {
  int idx = blockIdx.x * 256 + threadIdx.x;       // 0..4095
  float v0 = h0[idx * 2], v1 = h0[idx * 2 + 1];
  hex[idx] = packw(v0, v1, 0u);
}

__global__ __launch_bounds__(256, 1) void lstm_persist_fb(
    const float* __restrict__ x, const float* __restrict__ c0,
    const float* __restrict__ W, const float* __restrict__ bias,
    float* __restrict__ out, u64* __restrict__ hex) {

  __shared__ unsigned short hh_lds[32 * 264];
  __shared__ unsigned short hl_lds[32 * 264];
  __shared__ float zbuf[32 * 68];
  __shared__ unsigned short xlds[32 * 264];

  const int tid  = threadIdx.x;
  const int wg   = blockIdx.x;
  const int lane = tid & 63;
  const int wv   = tid >> 6;
  const int mt   = wv & 1;
  const int ct0  = (wv >> 1) * 2;
  const int q    = lane >> 4;
  const int mm   = lane & 15;

  short8 whh[2][8], whl[2][8], wx[2][8];
  float  bia[2];
  #pragma unroll
  for (int c = 0; c < 2; ++c) {
    const int col = (ct0 + c) * 256 + wg * 16 + mm;
    #pragma unroll
    for (int kc = 0; kc < 8; ++kc) {
      short8 vhh, vhl, vx;
      #pragma unroll
      for (int j = 0; j < 8; ++j) {
        int k = kc * 32 + q * 8 + j;
        float whv = W[(long)(256 + k) * 1024 + col];
        unsigned short hh = f2bf(whv);
        vhh[j] = (short)hh;
        vhl[j] = (short)f2bf(whv - bf2f(hh));
        vx[j] = (short)f2bf(W[(long)k * 1024 + col]);
      }
      whh[c][kc] = vhh; whl[c][kc] = vhl; wx[c][kc] = vx;
    }
    bia[c] = bias[(ct0 + c) * 256 + wg * 16 + mm];
  }

  const int cb  = tid >> 3;
  const int cu0 = (tid & 7) * 2;
  float cst[2];
  cst[0] = c0[cb * 256 + wg * 16 + cu0];
  cst[1] = c0[cb * 256 + wg * 16 + cu0 + 1];

  u64* const hex0 = hex;
  u64* const hex1 = hex + 4096;

  for (int t = 0; t < S_; ++t) {
    u64* const hsrc8 = (t & 1) ? hex1 : hex0;
    u64* const hdst8 = (t & 1) ? hex0 : hex1;
    const unsigned tagbit = (unsigned)((t >> 1) & 1);

    u64 hv[16];
    #pragma unroll
    for (int k = 0; k < 16; ++k)
      hv[k] = __hip_atomic_load(hsrc8 + (k << 8) + tid, __ATOMIC_RELAXED,
                                __HIP_MEMORY_SCOPE_AGENT);
    unsigned need = 0;
    #pragma unroll
    for (int k = 0; k < 16; ++k)
      if (((unsigned)(hv[k] >> 32) & 1u) != tagbit) need |= 1u << k;
    while (__ballot(need != 0u) != 0ull) {
      u64 tmp[16];
      #pragma unroll
      for (int k = 0; k < 16; ++k)
        if (need & (1u << k))
          tmp[k] = __hip_atomic_load(hsrc8 + (k << 8) + tid, __ATOMIC_RELAXED,
                                     __HIP_MEMORY_SCOPE_AGENT);
      #pragma unroll
      for (int k = 0; k < 16; ++k)
        if ((need & (1u << k)) && (((unsigned)(tmp[k] >> 32) & 1u) == tagbit)) {
          hv[k] = tmp[k];
          need &= ~(1u << k);
        }
    }

    #pragma unroll
    for (int k = 0; k < 16; ++k) {
      int b  = k * 2 + (tid >> 7);
      int du = (tid & 127);
      *(unsigned*)&hh_lds[b * 264 + du * 2] = (unsigned)hv[k];
      *(unsigned*)&hl_lds[b * 264 + du * 2] = (unsigned)(hv[k] >> 32);
    }
    {
      const int xb = tid >> 3, xi0 = (tid & 7) * 32;
      const float* xp = x + ((long)xb * S_ + t) * I_ + xi0;
      #pragma unroll
      for (int k2 = 0; k2 < 4; ++k2) {
        f32x4 a  = *(const f32x4*)(xp + k2 * 8);
        f32x4 b2 = *(const f32x4*)(xp + k2 * 8 + 4);
        unsigned short u8[8];
        #pragma unroll
        for (int j = 0; j < 4; ++j) { u8[j] = f2bf(a[j]); u8[4 + j] = f2bf(b2[j]); }
        *(uint4*)&xlds[xb * 264 + xi0 + k2 * 8] = *(const uint4*)u8;
      }
    }
    __syncthreads();

    f32x4 accH[2], accM[2], accX[2];
    #pragma unroll
    for (int c = 0; c < 2; ++c) {
      accH[c] = (f32x4){0.f, 0.f, 0.f, 0.f};
      accM[c] = (f32x4){0.f, 0.f, 0.f, 0.f};
      accX[c] = (f32x4){0.f, 0.f, 0.f, 0.f};
    }
    const int arow = mm + 16 * mt;
    #pragma unroll
    for (int kc = 0; kc < 8; ++kc) {
      short8 ahh = *(const short8*)&hh_lds[arow * 264 + kc * 32 + q * 8];
      short8 ahl = *(const short8*)&hl_lds[arow * 264 + kc * 32 + q * 8];
      short8 ax  = *(const short8*)&xlds[arow * 264 + kc * 32 + q * 8];
      #pragma unroll
      for (int c = 0; c < 2; ++c) {
        accH[c] = __builtin_amdgcn_mfma_f32_16x16x32_bf16(ahh, whh[c][kc], accH[c], 0, 0, 0);
        accM[c] = __builtin_amdgcn_mfma_f32_16x16x32_bf16(ahh, whl[c][kc], accM[c], 0, 0, 0);
        accM[c] = __builtin_amdgcn_mfma_f32_16x16x32_bf16(ahl, whh[c][kc], accM[c], 0, 0, 0);
        accX[c] = __builtin_amdgcn_mfma_f32_16x16x32_bf16(ax, wx[c][kc], accX[c], 0, 0, 0);
      }
    }
    #pragma unroll
    for (int c = 0; c < 2; ++c) {
      #pragma unroll
      for (int r = 0; r < 4; ++r) {
        float zp = accH[c][r] + accM[c][r] + accX[c][r] + bia[c];
        int brow = q * 4 + r + 16 * mt;
        zbuf[brow * 68 + (ct0 + c) * 16 + mm] = fast_tanh(zp);
      }
    }
    __syncthreads();

    float hn2[2];
    #pragma unroll
    for (int j = 0; j < 2; ++j) {
      int uu = cu0 + j;
      float zi = zbuf[cb * 68 +  0 + uu];
      float zf = zbuf[cb * 68 + 16 + uu];
      float zg = zbuf[cb * 68 + 32 + uu];
      float zo = zbuf[cb * 68 + 48 + uu];
      float ig = fast_sig(zi);
      float fg = fast_sig(zf);
      float gg = fast_tanh(zg);
      float og = fast_sig(zo);
      float cn = fg * cst[j] + ig * gg;
      cst[j] = cn;
      hn2[j] = fast_tanh(cn) * og;
    }
    *(float2*)(out + ((long)cb * S_ + t) * H_ + wg * 16 + cu0) =
        make_float2(hn2[0], hn2[1]);
    {
      const unsigned tagw = (unsigned)(((t + 1) >> 1) & 1);
      u64 word = packw(hn2[0], hn2[1], tagw);
      __hip_atomic_store(hdst8 + cb * 128 + wg * 8 + (cu0 >> 1), word,
                         __ATOMIC_RELAXED, __HIP_MEMORY_SCOPE_AGENT);
    }
  }
}

extern "C" void kernel_launch(void* const* d_in, const int* in_sizes, int n_in,
                              void* d_out, int out_size, void* d_ws, size_t ws_size,
                              hipStream_t stream) {
  const float* x    = (const float*)d_in[0];
  const float* h0   = (const float*)d_in[1];
  const float* c0   = (const float*)d_in[2];
  const float* W    = (const float*)d_in[3];
  const float* bias = (const float*)d_in[4];
  float* out = (float*)d_out;

  // ws layout: [0, 64K) h exchange, [64K, 64K+256M) zx
  u64*   hex = (u64*)d_ws;
  float* zx  = (float*)((char*)d_ws + 65536);
  const size_t zx_bytes = (size_t)S_ * B_ * 4 * H_ * sizeof(float);  // 256 MiB
  const int smem_bytes = 8 * 16896 + 8 * 1280;   // 145,408 B dynamic LDS

  // outputs 1 and 2 of the reference are zeros
  hipMemsetAsync((char*)d_out + (size_t)B_ * S_ * H_ * 4, 0, 2 * B_ * H_ * 4, stream);

  bool big_lds_ok =
      hipFuncSetAttribute((const void*)lstm_wave2,
                          hipFuncAttributeMaxDynamicSharedMemorySize,
                          smem_bytes) == hipSuccess;

  if (big_lds_ok && ws_size >= 65536 + zx_bytes) {
    // parity-1 half starts all-ones -> tag bit 1, invalid for its first
    // consumers (t=1, expected tag 0)
    hipMemsetAsync((char*)d_ws + 32768, 0xFF, 32768, stream);
    pack_h0_v<<<16, 256, 0, stream>>>(h0, hex);
    zx_precompute_v<<<(S_ / TC) * 32, 256, 0, stream>>>(x, W, bias, zx);
    lstm_wave2<<<16, 512, smem_bytes, stream>>>(c0, out, hex, W, zx);
  } else {
    hipMemsetAsync((char*)d_ws + 32768, 0xFF, 32768, stream);
    pack_h0_kernel<<<16, 256, 0, stream>>>(h0, hex);
    lstm_persist_fb<<<16, 256, 0, stream>>>(x, c0, W, bias, out, hex);
  }
}

// Round 5
// 7128.939 us; speedup vs baseline: 2.6438x; 2.6438x over previous
//
#include <hip/hip_runtime.h>
#include <hip/hip_bf16.h>
#include <type_traits>

// Problem constants
#define B_   32
#define S_   2048
#define I_   256
#define H_   256
#define NWG  16      // workgroups in the persistent kernel
#define NT   256     // threads per WG
#define UPW  16      // hidden units owned per WG (x4 gates = 64 columns)
#define TC   16      // timesteps per precompute WG

typedef __attribute__((ext_vector_type(8))) short short8;   // 8 x bf16 MFMA frag
typedef __attribute__((ext_vector_type(4))) float f32x4;
typedef unsigned long long u64;

__device__ __forceinline__ unsigned short f2bf(float f) {
  unsigned u = __builtin_bit_cast(unsigned, f);
  return (unsigned short)((u + 0x7FFFu + ((u >> 16) & 1u)) >> 16);  // RNE
}
__device__ __forceinline__ float bf2f(unsigned short b) {
  unsigned u = ((unsigned)b) << 16;
  return __builtin_bit_cast(float, u);
}
__device__ __forceinline__ float fast_rcp(float x) { return __builtin_amdgcn_rcpf(x); }
// |inputs| are bounded (<~8) in this net: no overflow concerns.
__device__ __forceinline__ float fast_tanh(float x) {
  return 1.f - 2.f * fast_rcp(__expf(2.f * x) + 1.f);
}
__device__ __forceinline__ float fast_sig(float x) {
  return fast_rcp(1.f + __expf(-x));
}
// Pack 2 hidden units into one exchange word: low dword = (hi0|hi1<<16),
// high dword = (lo0|lo1<<16) with tag in lo0's LSB.
__device__ __forceinline__ u64 packw(float v0, float v1, unsigned tagw) {
  unsigned short h0h = f2bf(v0);
  unsigned short h0l = f2bf(v0 - bf2f(h0h));
  unsigned short h1h = f2bf(v1);
  unsigned short h1l = f2bf(v1 - bf2f(h1h));
  unsigned hiw = (unsigned)h0h | ((unsigned)h1h << 16);
  unsigned low = (((unsigned)h0l & 0xFFFEu) | tagw) | ((unsigned)h1l << 16);
  return (u64)hiw | ((u64)low << 32);
}

// Barrier that does NOT drain vmcnt: LDS producer/consumer ordering only.
// __syncthreads() emits s_waitcnt vmcnt(0) before s_barrier, which drains the
// poll pre-blast + zx prefetch every phase (the round-1 serialization). All
// data staged through LDS is ordered by lgkmcnt(0); global loads in flight
// are consumed later via compiler-inserted counted vmcnt at first use.
// (Correctness precedent: round-2 kernel used this barrier in the same
// 4-wave lockstep and passed with identical absmax.)
__device__ __forceinline__ void bar_lds() {
  __builtin_amdgcn_sched_barrier(0);
  asm volatile("s_waitcnt lgkmcnt(0)" ::: "memory");
  __builtin_amdgcn_s_barrier();
  __builtin_amdgcn_sched_barrier(0);
}

// ===================== two-stream (batch-split) path =====================
// Exchange layout (u64 words): [A0:2048][A1:2048][B0:2048][B1:2048]
// group g, buffer (t&1): word = g*4096 + buf*2048 + b*128 + wg*8 + pair
// (b = batch-in-group 0..15, pair = unit-pair 0..7 within the WG's 16 units)

__global__ void pack_h0_2grp(const float* __restrict__ h0, u64* __restrict__ hex) {
  int idx = blockIdx.x * 256 + threadIdx.x;   // 0..4095
  int g   = idx >> 11;
  int rem = idx & 2047;
  int b   = rem >> 7;
  int u2  = rem & 127;
  const float* hp = h0 + ((g * 16 + b) * 256 + u2 * 2);
  hex[g * 4096 + rem] = packw(hp[0], hp[1], 0u);   // tag(t=0) = 0
}

// Full-chip precompute of zx = x@Wx + bias in the two-stream MFMA C-layout:
// element(t, g, ug, gate=wv, lane, r) at ((t*2+g)*16+ug)*1024 + wv*256 + lane*4 + r
__global__ __launch_bounds__(NT) void zx_precompute2(
    const float* __restrict__ x, const float* __restrict__ W,
    const float* __restrict__ bias, float* __restrict__ zx) {
  __shared__ unsigned short xlds[32 * 264];

  const int tid  = threadIdx.x;
  const int ug   = blockIdx.x & 15;
  const int tc   = blockIdx.x >> 4;
  const int lane = tid & 63;
  const int wv   = tid >> 6;     // wave = gate
  const int q    = lane >> 4;
  const int mm   = lane & 15;

  short8 wx[8];
  const int col = wv * 256 + ug * UPW + mm;
  const float bia = bias[col];
  #pragma unroll
  for (int kc = 0; kc < 8; ++kc) {
    short8 v;
    #pragma unroll
    for (int j = 0; j < 8; ++j)
      v[j] = (short)f2bf(W[(long)(kc * 32 + q * 8 + j) * 1024 + col]);
    wx[kc] = v;
  }

  for (int tt = 0; tt < TC; ++tt) {
    const int t = tc * TC + tt;
    const int xb = tid >> 3, xi0 = (tid & 7) * 32;
    const float* xp = x + ((long)xb * S_ + t) * I_ + xi0;
    #pragma unroll
    for (int k2 = 0; k2 < 4; ++k2) {
      f32x4 a  = *(const f32x4*)(xp + k2 * 8);
      f32x4 b2 = *(const f32x4*)(xp + k2 * 8 + 4);
      unsigned short u8[8];
      #pragma unroll
      for (int j = 0; j < 4; ++j) { u8[j] = f2bf(a[j]); u8[4 + j] = f2bf(b2[j]); }
      *(uint4*)&xlds[xb * 264 + xi0 + k2 * 8] = *(const uint4*)u8;
    }
    __syncthreads();
    f32x4 acc0 = {0.f, 0.f, 0.f, 0.f}, acc1 = {0.f, 0.f, 0.f, 0.f};
    #pragma unroll
    for (int kc = 0; kc < 8; ++kc) {
      short8 a0 = *(const short8*)&xlds[(mm)      * 264 + kc * 32 + q * 8];
      short8 a1 = *(const short8*)&xlds[(16 + mm) * 264 + kc * 32 + q * 8];
      acc0 = __builtin_amdgcn_mfma_f32_16x16x32_bf16(a0, wx[kc], acc0, 0, 0, 0);
      acc1 = __builtin_amdgcn_mfma_f32_16x16x32_bf16(a1, wx[kc], acc1, 0, 0, 0);
    }
    f32x4 s0, s1;
    #pragma unroll
    for (int r = 0; r < 4; ++r) { s0[r] = acc0[r] + bia; s1[r] = acc1[r] + bia; }
    *(f32x4*)(zx + (((long)t * 2 + 0) * 16 + ug) * 1024 + wv * 256 + lane * 4) = s0;
    *(f32x4*)(zx + (((long)t * 2 + 1) * 16 + ug) * 1024 + wv * 256 + lane * 4) = s1;
    __syncthreads();   // protect xlds before next stage
  }
}

// Persistent two-stream LSTM. Batches split into two independent M=16 groups;
// phases interleave so each group's exchange RT hides under the other's
// compute. Per-phase barriers are lgkm-only: poll pre-blast and zx prefetch
// stay in flight across them (counted vmcnt at first use, a phase later).
__global__ __launch_bounds__(NT, 1) void lstm_persist2(
    const float* __restrict__ h0, const float* __restrict__ c0,
    float* __restrict__ out, u64* __restrict__ hex,
    const float* __restrict__ W, const float* __restrict__ zx) {

  __shared__ unsigned short hh_lds[16 * 264];   // hi plane (one group)
  __shared__ unsigned short hl_lds[16 * 264];   // lo plane
  __shared__ float zbuf[16 * 68];
  __shared__ u64 ownw[2][128];                  // this WG's own words, per group

  const int tid  = threadIdx.x;
  const int wg   = blockIdx.x;
  const int lane = tid & 63;
  const int wv   = tid >> 6;          // wave = gate (0..3)
  const int q    = lane >> 4;
  const int mm   = lane & 15;
  // this thread's polled unit-pair column is fixed (u2 = tid&127); if it falls
  // in our own WG's slice we never poll globally for it.
  const bool own = (((tid & 127) >> 3) == wg);

  // ---- one-time: Wh fragments (hi/lo bf16) for this wave's gate
  short8 whh[8], whl[8];
  const int col = wv * 256 + wg * UPW + mm;
  #pragma unroll
  for (int kc = 0; kc < 8; ++kc) {
    short8 vhh, vhl;
    #pragma unroll
    for (int j = 0; j < 8; ++j) {
      int k = kc * 32 + q * 8 + j;
      float whv = W[(long)(256 + k) * 1024 + col];
      unsigned short hhb = f2bf(whv);
      vhh[j] = (short)hhb;
      vhl[j] = (short)f2bf(whv - bf2f(hhb));
    }
    whh[kc] = vhh; whl[kc] = vhl;
  }

  // combine-phase ownership (tid<128): batch-in-group cb, unit pair cu0
  const int cb  = tid >> 3;
  const int cu0 = (tid & 7) * 2;
  float cs0[2], cs1[2];
  if (tid < 128) {
    cs0[0] = c0[(0 * 16 + cb) * 256 + wg * UPW + cu0];
    cs0[1] = c0[(0 * 16 + cb) * 256 + wg * UPW + cu0 + 1];
    cs1[0] = c0[(1 * 16 + cb) * 256 + wg * UPW + cu0];
    cs1[1] = c0[(1 * 16 + cb) * 256 + wg * UPW + cu0 + 1];
    // seed own-word LDS with h0 (identical packing to the global words)
    #pragma unroll
    for (int g = 0; g < 2; ++g) {
      float v0 = h0[(g * 16 + cb) * 256 + wg * UPW + cu0];
      float v1 = h0[(g * 16 + cb) * 256 + wg * UPW + cu0 + 1];
      ownw[g][cb * 8 + (cu0 >> 1)] = packw(v0, v1, 0u);
    }
  }

  u64 hvA[8], hvB[8];
  // pre-blast G0 t=0 (buffer 0, filled by pack_h0_2grp)
  if (!own) {
    #pragma unroll
    for (int k = 0; k < 8; ++k)
      hvA[k] = __hip_atomic_load(hex + (k << 8) + tid, __ATOMIC_RELAXED,
                                 __HIP_MEMORY_SCOPE_AGENT);
  }

  f32x4 zxv0 = *(const f32x4*)(zx + ((long)0 * 16 + wg) * 1024 + wv * 256 + lane * 4);
  f32x4 zxv1 = *(const f32x4*)(zx + ((long)1 * 16 + wg) * 1024 + wv * 256 + lane * 4);
  f32x4 zxn0, zxn1;

  __syncthreads();   // one-time full sync (ownw + cs visible)

  for (int t = 0; t < S_; ++t) {
    const unsigned tagbit = (unsigned)((t >> 1) & 1);

    auto phase = [&](auto gc, u64 (&hvC)[8], u64 (&hvN)[8],
                     f32x4& zv, f32x4& zn, float (&cs)[2]) {
      constexpr int g = gc.value;

      // 1. tag-check the pre-blasted words; retry only stale words
      if (!own) {
        u64* hsrc = hex + g * 4096 + (t & 1) * 2048;
        unsigned need = 0;
        #pragma unroll
        for (int k = 0; k < 8; ++k)
          if (((unsigned)(hvC[k] >> 32) & 1u) != tagbit) need |= 1u << k;
        while (__ballot(need != 0u) != 0ull) {
          u64 tmp[8];
          #pragma unroll
          for (int k = 0; k < 8; ++k)
            if (need & (1u << k))
              tmp[k] = __hip_atomic_load(hsrc + (k << 8) + tid, __ATOMIC_RELAXED,
                                         __HIP_MEMORY_SCOPE_AGENT);
          #pragma unroll
          for (int k = 0; k < 8; ++k)
            if ((need & (1u << k)) && (((unsigned)(tmp[k] >> 32) & 1u) == tagbit)) {
              hvC[k] = tmp[k];
              need &= ~(1u << k);
            }
        }
      }

      // 2. stage h into split hi/lo LDS planes (own slice straight from LDS)
      #pragma unroll
      for (int k = 0; k < 8; ++k) {
        int b  = k * 2 + (tid >> 7);
        int u2 = tid & 127;
        u64 w = own ? ownw[g][b * 8 + (tid & 7)] : hvC[k];
        *(unsigned*)&hh_lds[b * 264 + u2 * 2] = (unsigned)w;
        *(unsigned*)&hl_lds[b * 264 + u2 * 2] = (unsigned)(w >> 32);
      }

      // 3. pipelined pre-blast of the NEXT phase's words; stays in flight
      //    across the lgkm-only barriers, consumed a full phase later.
      if (!own) {
        u64* bsrc = (g == 0) ? (hex + 4096 + (t & 1) * 2048)     // G1, step t
                             : (hex + ((t + 1) & 1) * 2048);     // G0, step t+1
        #pragma unroll
        for (int k = 0; k < 8; ++k)
          hvN[k] = __hip_atomic_load(bsrc + (k << 8) + tid, __ATOMIC_RELAXED,
                                     __HIP_MEMORY_SCOPE_AGENT);
      }
      bar_lds();   // SYNC1: staging complete (no vmcnt drain)

      // 4. zx prefetch for t+1 (consumed next iteration; flies across barriers)
      {
        int tn = (t + 1 < S_) ? (t + 1) : t;
        zn = *(const f32x4*)(zx + (((long)tn * 2 + g) * 16 + wg) * 1024 +
                             wv * 256 + lane * 4);
      }

      // 5. MFMA: accH (hi*hi) + accM (hi*lo + lo*hi), M=16 batches of group g
      f32x4 accH = {0.f, 0.f, 0.f, 0.f}, accM = {0.f, 0.f, 0.f, 0.f};
      #pragma unroll
      for (int kc = 0; kc < 8; ++kc) {
        short8 ahh = *(const short8*)&hh_lds[mm * 264 + kc * 32 + q * 8];
        short8 ahl = *(const short8*)&hl_lds[mm * 264 + kc * 32 + q * 8];
        accH = __builtin_amdgcn_mfma_f32_16x16x32_bf16(ahh, whh[kc], accH, 0, 0, 0);
        accM = __builtin_amdgcn_mfma_f32_16x16x32_bf16(ahh, whl[kc], accM, 0, 0, 0);
        accM = __builtin_amdgcn_mfma_f32_16x16x32_bf16(ahl, whh[kc], accM, 0, 0, 0);
      }
      #pragma unroll
      for (int r = 0; r < 4; ++r) {
        float zp = accH[r] + accM[r];
        zp += zv[r];
        zbuf[(q * 4 + r) * 68 + wv * 16 + mm] = fast_tanh(zp);
      }
      bar_lds();   // SYNC2: zbuf complete (no vmcnt drain)

      // 6. combine: gates + cell/hidden update; publish FIRST (critical path)
      if (tid < 128) {
        float hn2[2];
        #pragma unroll
        for (int j = 0; j < 2; ++j) {
          int u = cu0 + j;
          float zi = zbuf[cb * 68 +  0 + u];
          float zf = zbuf[cb * 68 + 16 + u];
          float zg = zbuf[cb * 68 + 32 + u];
          float zo = zbuf[cb * 68 + 48 + u];
          float ig = fast_sig(zi);
          float fg = fast_sig(zf);
          float gg = fast_tanh(zg);
          float og = fast_sig(zo);
          float cn = fg * cs[j] + ig * gg;
          cs[j] = cn;
          hn2[j] = fast_tanh(cn) * og;
        }
        const unsigned tagw = (unsigned)(((t + 1) >> 1) & 1);
        u64 word = packw(hn2[0], hn2[1], tagw);
        __hip_atomic_store(hex + g * 4096 + ((t + 1) & 1) * 2048 +
                               cb * 128 + wg * 8 + (cu0 >> 1),
                           word, __ATOMIC_RELAXED, __HIP_MEMORY_SCOPE_AGENT);
        ownw[g][cb * 8 + (cu0 >> 1)] = word;
        int gb = g * 16 + cb;
        *(float2*)(out + ((long)gb * S_ + t) * H_ + wg * UPW + cu0) =
            make_float2(hn2[0], hn2[1]);
      }
    };

    phase(std::integral_constant<int, 0>{}, hvA, hvB, zxv0, zxn0, cs0);
    phase(std::integral_constant<int, 1>{}, hvB, hvA, zxv1, zxn1, cs1);
    zxv0 = zxn0; zxv1 = zxn1;
  }
}

// ===================== legacy fallback (small-workspace) path =====================

__global__ void pack_h0_kernel(const float* __restrict__ h0, u64* __restrict__ hex) {
  int idx = blockIdx.x * 256 + threadIdx.x;       // 0..4095
  float v0 = h0[idx * 2], v1 = h0[idx * 2 + 1];
  hex[idx] = packw(v0, v1, 0u);
}

__global__ __launch_bounds__(NT, 1) void lstm_persist_fb(
    const float* __restrict__ x, const float* __restrict__ c0,
    const float* __restrict__ W, const float* __restrict__ bias,
    float* __restrict__ out, u64* __restrict__ hex) {

  __shared__ unsigned short hh_lds[32 * 264];
  __shared__ unsigned short hl_lds[32 * 264];
  __shared__ float zbuf[32 * 68];
  __shared__ unsigned short xlds[32 * 264];

  const int tid  = threadIdx.x;
  const int wg   = blockIdx.x;
  const int lane = tid & 63;
  const int wv   = tid >> 6;
  const int mt   = wv & 1;
  const int ct0  = (wv >> 1) * 2;
  const int q    = lane >> 4;
  const int mm   = lane & 15;

  short8 whh[2][8], whl[2][8], wx[2][8];
  float  bia[2];
  #pragma unroll
  for (int c = 0; c < 2; ++c) {
    const int col = (ct0 + c) * 256 + wg * UPW + mm;
    #pragma unroll
    for (int kc = 0; kc < 8; ++kc) {
      short8 vhh, vhl, vx;
      #pragma unroll
      for (int j = 0; j < 8; ++j) {
        int k = kc * 32 + q * 8 + j;
        float whv = W[(long)(256 + k) * 1024 + col];
        unsigned short hh = f2bf(whv);
        vhh[j] = (short)hh;
        vhl[j] = (short)f2bf(whv - bf2f(hh));
        vx[j] = (short)f2bf(W[(long)k * 1024 + col]);
      }
      whh[c][kc] = vhh; whl[c][kc] = vhl; wx[c][kc] = vx;
    }
    bia[c] = bias[(ct0 + c) * 256 + wg * UPW + mm];
  }

  const int cb  = tid >> 3;
  const int cu0 = (tid & 7) * 2;
  float cst[2];
  cst[0] = c0[cb * 256 + wg * UPW + cu0];
  cst[1] = c0[cb * 256 + wg * UPW + cu0 + 1];

  u64* const hex0 = hex;
  u64* const hex1 = hex + 4096;

  for (int t = 0; t < S_; ++t) {
    u64* const hsrc8 = (t & 1) ? hex1 : hex0;
    u64* const hdst8 = (t & 1) ? hex0 : hex1;
    const unsigned tagbit = (unsigned)((t >> 1) & 1);

    u64 hv[16];
    #pragma unroll
    for (int k = 0; k < 16; ++k)
      hv[k] = __hip_atomic_load(hsrc8 + (k << 8) + tid, __ATOMIC_RELAXED,
                                __HIP_MEMORY_SCOPE_AGENT);
    unsigned need = 0;
    #pragma unroll
    for (int k = 0; k < 16; ++k)
      if (((unsigned)(hv[k] >> 32) & 1u) != tagbit) need |= 1u << k;
    while (__ballot(need != 0u) != 0ull) {
      u64 tmp[16];
      #pragma unroll
      for (int k = 0; k < 16; ++k)
        if (need & (1u << k))
          tmp[k] = __hip_atomic_load(hsrc8 + (k << 8) + tid, __ATOMIC_RELAXED,
                                     __HIP_MEMORY_SCOPE_AGENT);
      #pragma unroll
      for (int k = 0; k < 16; ++k)
        if ((need & (1u << k)) && (((unsigned)(tmp[k] >> 32) & 1u) == tagbit)) {
          hv[k] = tmp[k];
          need &= ~(1u << k);
        }
    }

    #pragma unroll
    for (int k = 0; k < 16; ++k) {
      int b  = k * 2 + (tid >> 7);
      int du = (tid & 127);
      *(unsigned*)&hh_lds[b * 264 + du * 2] = (unsigned)hv[k];
      *(unsigned*)&hl_lds[b * 264 + du * 2] = (unsigned)(hv[k] >> 32);
    }
    {
      const int xb = tid >> 3, xi0 = (tid & 7) * 32;
      const float* xp = x + ((long)xb * S_ + t) * I_ + xi0;
      #pragma unroll
      for (int k2 = 0; k2 < 4; ++k2) {
        f32x4 a  = *(const f32x4*)(xp + k2 * 8);
        f32x4 b2 = *(const f32x4*)(xp + k2 * 8 + 4);
        unsigned short u8[8];
        #pragma unroll
        for (int j = 0; j < 4; ++j) { u8[j] = f2bf(a[j]); u8[4 + j] = f2bf(b2[j]); }
        *(uint4*)&xlds[xb * 264 + xi0 + k2 * 8] = *(const uint4*)u8;
      }
    }
    __syncthreads();

    f32x4 accH[2], accM[2], accX[2];
    #pragma unroll
    for (int c = 0; c < 2; ++c) {
      accH[c] = (f32x4){0.f, 0.f, 0.f, 0.f};
      accM[c] = (f32x4){0.f, 0.f, 0.f, 0.f};
      accX[c] = (f32x4){0.f, 0.f, 0.f, 0.f};
    }
    const int arow = mm + 16 * mt;
    #pragma unroll
    for (int kc = 0; kc < 8; ++kc) {
      short8 ahh = *(const short8*)&hh_lds[arow * 264 + kc * 32 + q * 8];
      short8 ahl = *(const short8*)&hl_lds[arow * 264 + kc * 32 + q * 8];
      short8 ax  = *(const short8*)&xlds[arow * 264 + kc * 32 + q * 8];
      #pragma unroll
      for (int c = 0; c < 2; ++c) {
        accH[c] = __builtin_amdgcn_mfma_f32_16x16x32_bf16(ahh, whh[c][kc], accH[c], 0, 0, 0);
        accM[c] = __builtin_amdgcn_mfma_f32_16x16x32_bf16(ahh, whl[c][kc], accM[c], 0, 0, 0);
        accM[c] = __builtin_amdgcn_mfma_f32_16x16x32_bf16(ahl, whh[c][kc], accM[c], 0, 0, 0);
        accX[c] = __builtin_amdgcn_mfma_f32_16x16x32_bf16(ax, wx[c][kc], accX[c], 0, 0, 0);
      }
    }
    #pragma unroll
    for (int c = 0; c < 2; ++c) {
      #pragma unroll
      for (int r = 0; r < 4; ++r) {
        float zp = accH[c][r] + accM[c][r] + accX[c][r] + bia[c];
        int brow = q * 4 + r + 16 * mt;
        zbuf[brow * 68 + (ct0 + c) * 16 + mm] = fast_tanh(zp);
      }
    }
    __syncthreads();

    float hn2[2];
    #pragma unroll
    for (int j = 0; j < 2; ++j) {
      int u = cu0 + j;
      float zi = zbuf[cb * 68 +  0 + u];
      float zf = zbuf[cb * 68 + 16 + u];
      float zg = zbuf[cb * 68 + 32 + u];
      float zo = zbuf[cb * 68 + 48 + u];
      float ig = fast_sig(zi);
      float fg = fast_sig(zf);
      float gg = fast_tanh(zg);
      float og = fast_sig(zo);
      float cn = fg * cst[j] + ig * gg;
      cst[j] = cn;
      hn2[j] = fast_tanh(cn) * og;
    }
    *(float2*)(out + ((long)cb * S_ + t) * H_ + wg * UPW + cu0) =
        make_float2(hn2[0], hn2[1]);
    {
      const unsigned tagw = (unsigned)(((t + 1) >> 1) & 1);
      u64 word = packw(hn2[0], hn2[1], tagw);
      __hip_atomic_store(hdst8 + cb * 128 + wg * 8 + (cu0 >> 1), word,
                         __ATOMIC_RELAXED, __HIP_MEMORY_SCOPE_AGENT);
    }
  }
}

extern "C" void kernel_launch(void* const* d_in, const int* in_sizes, int n_in,
                              void* d_out, int out_size, void* d_ws, size_t ws_size,
                              hipStream_t stream) {
  const float* x    = (const float*)d_in[0];
  const float* h0   = (const float*)d_in[1];
  const float* c0   = (const float*)d_in[2];
  const float* W    = (const float*)d_in[3];
  const float* bias = (const float*)d_in[4];
  float* out = (float*)d_out;

  // ws layout: [0, 64K) h exchange, [64K, 64K+256M) zx
  u64*   hex = (u64*)d_ws;
  float* zx  = (float*)((char*)d_ws + 65536);
  const size_t zx_bytes = (size_t)S_ * B_ * 4 * H_ * sizeof(float);  // 256 MiB

  // outputs 1 and 2 of the reference are zeros
  hipMemsetAsync((char*)d_out + (size_t)B_ * S_ * H_ * 4, 0, 2 * B_ * H_ * 4, stream);

  if (ws_size >= 65536 + zx_bytes) {
    // two-stream exchange: [A0 16K][A1 16K][B0 16K][B1 16K]; odd buffers start
    // all-ones -> tag bit 1, invalid for their first consumers (t=1, tag 0)
    hipMemsetAsync((char*)d_ws + 16384, 0xFF, 16384, stream);
    hipMemsetAsync((char*)d_ws + 49152, 0xFF, 16384, stream);
    pack_h0_2grp<<<16, 256, 0, stream>>>(h0, hex);
    zx_precompute2<<<(S_ / TC) * 16, NT, 0, stream>>>(x, W, bias, zx);
    lstm_persist2<<<NWG, NT, 0, stream>>>(h0, c0, out, hex, W, zx);
  } else {
    hipMemsetAsync((char*)d_ws + 32768, 0xFF, 32768, stream);
    pack_h0_kernel<<<16, 256, 0, stream>>>(h0, hex);
    lstm_persist_fb<<<NWG, NT, 0, stream>>>(x, c0, W, bias, out, hex);
  }
}

// Round 6
// 5293.962 us; speedup vs baseline: 3.5602x; 1.3466x over previous
//
#include <hip/hip_runtime.h>
#include <hip/hip_bf16.h>

// Problem constants
#define B_   32
#define S_   2048
#define I_   256
#define H_   256
#define NT   256     // threads per WG
#define UPW  16      // hidden units owned per WG (x4 gates = 64 columns)
#define TC   16      // timesteps per precompute WG

typedef __attribute__((ext_vector_type(8))) short short8;   // 8 x bf16 MFMA frag
typedef __attribute__((ext_vector_type(4))) float f32x4;
typedef unsigned long long u64;

__device__ __forceinline__ unsigned short f2bf(float f) {
  unsigned u = __builtin_bit_cast(unsigned, f);
  return (unsigned short)((u + 0x7FFFu + ((u >> 16) & 1u)) >> 16);  // RNE
}
__device__ __forceinline__ float bf2f(unsigned short b) {
  unsigned u = ((unsigned)b) << 16;
  return __builtin_bit_cast(float, u);
}
__device__ __forceinline__ float fast_rcp(float x) { return __builtin_amdgcn_rcpf(x); }
// |inputs| are bounded (<~8) in this net: no overflow concerns.
__device__ __forceinline__ float fast_tanh(float x) {
  return 1.f - 2.f * fast_rcp(__expf(2.f * x) + 1.f);
}
__device__ __forceinline__ float fast_sig(float x) {
  return fast_rcp(1.f + __expf(-x));
}
// Pack 2 hidden units into one exchange word: low dword = (hi0|hi1<<16),
// high dword = (lo0|lo1<<16) with tag in lo0's LSB.
__device__ __forceinline__ u64 packw(float v0, float v1, unsigned tagw) {
  unsigned short h0h = f2bf(v0);
  unsigned short h0l = f2bf(v0 - bf2f(h0h));
  unsigned short h1h = f2bf(v1);
  unsigned short h1l = f2bf(v1 - bf2f(h1h));
  unsigned hiw = (unsigned)h0h | ((unsigned)h1h << 16);
  unsigned low = (((unsigned)h0l & 0xFFFEu) | tagw) | ((unsigned)h1l << 16);
  return (u64)hiw | ((u64)low << 32);
}

// Barrier that does NOT drain vmcnt: LDS producer/consumer ordering only.
// Keeps poll pre-blast + zx prefetch in flight across the barrier.
__device__ __forceinline__ void bar_lds() {
  __builtin_amdgcn_sched_barrier(0);
  asm volatile("s_waitcnt lgkmcnt(0)" ::: "memory");
  __builtin_amdgcn_s_barrier();
  __builtin_amdgcn_sched_barrier(0);
}

// ===================== group-split (32-WG) path =====================
// 32 WGs = (group g in {0,1}) x (unit-slice wg in 0..15). Groups are fully
// independent recurrence chains running on DISJOINT CUs, so wall/step is ONE
// group's chain latency (publish -> MALL visibility -> poll -> stage -> MFMA
// -> combine), not the sum of two interleaved program phases (rounds 1/5).
// Per-consumer poll breadth = 8 words/thread (same as round 1; round 4's
// failure was 64x that).
//
// Exchange layout (u64 words): [G0p0:2048][G0p1:2048][G1p0:2048][G1p1:2048]
// word = g*4096 + (t&1)*2048 + b*128 + wg*8 + pair. Validity: tag bit
// (lo0 LSB) == (t>>1)&1. 2-buffer overwrite safety: a producer publishes
// h(t+2) only after consuming all of h(t+1), whose producers consumed all
// of h(t) first -> no consumer still needs the word being overwritten.

__global__ void pack_h0_2grp(const float* __restrict__ h0, u64* __restrict__ hex) {
  int idx = blockIdx.x * 256 + threadIdx.x;   // 0..4095
  int g   = idx >> 11;
  int rem = idx & 2047;
  int b   = rem >> 7;
  int u2  = rem & 127;
  const float* hp = h0 + ((g * 16 + b) * 256 + u2 * 2);
  hex[g * 4096 + rem] = packw(hp[0], hp[1], 0u);   // tag(t=0) = 0
}

// Full-chip precompute of zx = x@Wx + bias in the two-stream MFMA C-layout:
// element(t, g, ug, gate=wv, lane, r) at ((t*2+g)*16+ug)*1024 + wv*256 + lane*4 + r
__global__ __launch_bounds__(NT) void zx_precompute2(
    const float* __restrict__ x, const float* __restrict__ W,
    const float* __restrict__ bias, float* __restrict__ zx) {
  __shared__ unsigned short xlds[32 * 264];

  const int tid  = threadIdx.x;
  const int ug   = blockIdx.x & 15;
  const int tc   = blockIdx.x >> 4;
  const int lane = tid & 63;
  const int wv   = tid >> 6;     // wave = gate
  const int q    = lane >> 4;
  const int mm   = lane & 15;

  short8 wx[8];
  const int col = wv * 256 + ug * UPW + mm;
  const float bia = bias[col];
  #pragma unroll
  for (int kc = 0; kc < 8; ++kc) {
    short8 v;
    #pragma unroll
    for (int j = 0; j < 8; ++j)
      v[j] = (short)f2bf(W[(long)(kc * 32 + q * 8 + j) * 1024 + col]);
    wx[kc] = v;
  }

  for (int tt = 0; tt < TC; ++tt) {
    const int t = tc * TC + tt;
    const int xb = tid >> 3, xi0 = (tid & 7) * 32;
    const float* xp = x + ((long)xb * S_ + t) * I_ + xi0;
    #pragma unroll
    for (int k2 = 0; k2 < 4; ++k2) {
      f32x4 a  = *(const f32x4*)(xp + k2 * 8);
      f32x4 b2 = *(const f32x4*)(xp + k2 * 8 + 4);
      unsigned short u8[8];
      #pragma unroll
      for (int j = 0; j < 4; ++j) { u8[j] = f2bf(a[j]); u8[4 + j] = f2bf(b2[j]); }
      *(uint4*)&xlds[xb * 264 + xi0 + k2 * 8] = *(const uint4*)u8;
    }
    __syncthreads();
    f32x4 acc0 = {0.f, 0.f, 0.f, 0.f}, acc1 = {0.f, 0.f, 0.f, 0.f};
    #pragma unroll
    for (int kc = 0; kc < 8; ++kc) {
      short8 a0 = *(const short8*)&xlds[(mm)      * 264 + kc * 32 + q * 8];
      short8 a1 = *(const short8*)&xlds[(16 + mm) * 264 + kc * 32 + q * 8];
      acc0 = __builtin_amdgcn_mfma_f32_16x16x32_bf16(a0, wx[kc], acc0, 0, 0, 0);
      acc1 = __builtin_amdgcn_mfma_f32_16x16x32_bf16(a1, wx[kc], acc1, 0, 0, 0);
    }
    f32x4 s0, s1;
    #pragma unroll
    for (int r = 0; r < 4; ++r) { s0[r] = acc0[r] + bia; s1[r] = acc1[r] + bia; }
    *(f32x4*)(zx + (((long)t * 2 + 0) * 16 + ug) * 1024 + wv * 256 + lane * 4) = s0;
    *(f32x4*)(zx + (((long)t * 2 + 1) * 16 + ug) * 1024 + wv * 256 + lane * 4) = s1;
    __syncthreads();   // protect xlds before next stage
  }
}

// Persistent group-split LSTM. One WG per (group, unit-slice); single-group
// step loop; groups overlap on disjoint CUs.
__global__ __launch_bounds__(NT, 1) void lstm_split(
    const float* __restrict__ h0, const float* __restrict__ c0,
    float* __restrict__ out, u64* __restrict__ hex,
    const float* __restrict__ W, const float* __restrict__ zx) {

  __shared__ unsigned short hh_lds[16 * 264];   // hi plane
  __shared__ unsigned short hl_lds[16 * 264];   // lo plane
  __shared__ float zbuf[16 * 68];

  const int tid  = threadIdx.x;
  const int wg   = blockIdx.x & 15;   // unit-slice
  const int g    = blockIdx.x >> 4;   // batch group
  const int lane = tid & 63;
  const int wv   = tid >> 6;          // wave = gate (0..3)
  const int q    = lane >> 4;
  const int mm   = lane & 15;
  // this thread's polled unit-pair column is fixed (u2 = tid&127); if it falls
  // in our own WG's slice we never poll/stage it -- combine writes those
  // columns of hh/hl directly (ordered vs the next MFMA by SYNC1).
  const bool own = (((tid & 127) >> 3) == wg);

  u64* const gex = hex + g * 4096;

  // ---- one-time: Wh fragments (hi/lo bf16) for this wave's gate
  short8 whh[8], whl[8];
  const int col = wv * 256 + wg * UPW + mm;
  #pragma unroll
  for (int kc = 0; kc < 8; ++kc) {
    short8 vhh, vhl;
    #pragma unroll
    for (int j = 0; j < 8; ++j) {
      int k = kc * 32 + q * 8 + j;
      float whv = W[(long)(256 + k) * 1024 + col];
      unsigned short hhb = f2bf(whv);
      vhh[j] = (short)hhb;
      vhl[j] = (short)f2bf(whv - bf2f(hhb));
    }
    whh[kc] = vhh; whl[kc] = vhl;
  }

  // combine ownership: thread owns (batch-in-group cb, unit cu)
  const int cb = tid >> 4;            // 0..15
  const int cu = tid & 15;            // 0..15
  float cs = c0[(g * 16 + cb) * 256 + wg * UPW + cu];

  // seed own columns of hh/hl from h0 (identical packing to exchange words)
  if ((cu & 1) == 0) {
    float v0 = h0[(g * 16 + cb) * 256 + wg * UPW + cu];
    float v1 = h0[(g * 16 + cb) * 256 + wg * UPW + cu + 1];
    u64 word = packw(v0, v1, 0u);
    const int co = (wg * 8 + (cu >> 1)) * 2;
    *(unsigned*)&hh_lds[cb * 264 + co] = (unsigned)word;
    *(unsigned*)&hl_lds[cb * 264 + co] = (unsigned)(word >> 32);
  }

  // pre-blast t=0 words (parity 0, seeded by pack_h0_2grp; stream-ordered)
  u64 hv[8];
  if (!own) {
    #pragma unroll
    for (int k = 0; k < 8; ++k)
      hv[k] = __hip_atomic_load(gex + (k << 8) + tid, __ATOMIC_RELAXED,
                                __HIP_MEMORY_SCOPE_AGENT);
  }

  f32x4 zxv = *(const f32x4*)(zx + ((long)(0 * 2 + g) * 16 + wg) * 1024 +
                              wv * 256 + lane * 4);
  f32x4 zxn;

  __syncthreads();   // one-time full sync (h0 seed columns visible)

  for (int t = 0; t < S_; ++t) {
    const unsigned tagbit = (unsigned)((t >> 1) & 1);

    // 1. tag-check the pre-blasted words; retry only stale words.
    //    Each retry round self-throttles on its own load round trip.
    if (!own) {
      u64* hsrc = gex + (t & 1) * 2048;
      unsigned need = 0;
      #pragma unroll
      for (int k = 0; k < 8; ++k)
        if (((unsigned)(hv[k] >> 32) & 1u) != tagbit) need |= 1u << k;
      while (__ballot(need != 0u) != 0ull) {
        u64 tmp[8];
        #pragma unroll
        for (int k = 0; k < 8; ++k)
          if (need & (1u << k))
            tmp[k] = __hip_atomic_load(hsrc + (k << 8) + tid, __ATOMIC_RELAXED,
                                       __HIP_MEMORY_SCOPE_AGENT);
        #pragma unroll
        for (int k = 0; k < 8; ++k)
          if ((need & (1u << k)) && (((unsigned)(tmp[k] >> 32) & 1u) == tagbit)) {
            hv[k] = tmp[k];
            need &= ~(1u << k);
          }
      }
      // 2. stage h into split hi/lo LDS planes (own columns already written
      //    by combine at the end of step t-1, ordered by SYNC1 below)
      #pragma unroll
      for (int k = 0; k < 8; ++k) {
        int b  = k * 2 + (tid >> 7);
        int u2 = tid & 127;
        *(unsigned*)&hh_lds[b * 264 + u2 * 2] = (unsigned)hv[k];
        *(unsigned*)&hl_lds[b * 264 + u2 * 2] = (unsigned)(hv[k] >> 32);
      }
    }
    bar_lds();   // SYNC1: staging complete (no vmcnt drain)

    // 3. MFMA: accH (hi*hi) + accM (hi*lo + lo*hi), M=16 batches, this group
    f32x4 accH = {0.f, 0.f, 0.f, 0.f}, accM = {0.f, 0.f, 0.f, 0.f};
    #pragma unroll
    for (int kc = 0; kc < 8; ++kc) {
      short8 ahh = *(const short8*)&hh_lds[mm * 264 + kc * 32 + q * 8];
      short8 ahl = *(const short8*)&hl_lds[mm * 264 + kc * 32 + q * 8];
      accH = __builtin_amdgcn_mfma_f32_16x16x32_bf16(ahh, whh[kc], accH, 0, 0, 0);
      accM = __builtin_amdgcn_mfma_f32_16x16x32_bf16(ahh, whl[kc], accM, 0, 0, 0);
      accM = __builtin_amdgcn_mfma_f32_16x16x32_bf16(ahl, whh[kc], accM, 0, 0, 0);
    }
    #pragma unroll
    for (int r = 0; r < 4; ++r)
      zbuf[(q * 4 + r) * 68 + wv * 16 + mm] = fast_tanh(accH[r] + accM[r] + zxv[r]);

    // zx prefetch for t+1 (stays in flight across SYNC2 + combine + next poll)
    {
      int tn = (t + 1 < S_) ? (t + 1) : t;
      zxn = *(const f32x4*)(zx + (((long)tn * 2 + g) * 16 + wg) * 1024 +
                            wv * 256 + lane * 4);
    }
    bar_lds();   // SYNC2: zbuf complete (no vmcnt drain)

    // 4. combine: all 256 threads, one unit each; publish FIRST
    float zi = zbuf[cb * 68 +  0 + cu];
    float zf = zbuf[cb * 68 + 16 + cu];
    float zg = zbuf[cb * 68 + 32 + cu];
    float zo = zbuf[cb * 68 + 48 + cu];
    float ig = fast_sig(zi);
    float fg = fast_sig(zf);
    float gg = fast_tanh(zg);
    float og = fast_sig(zo);
    float cn = fg * cs + ig * gg;
    cs = cn;
    float hn = fast_tanh(cn) * og;
    float hp = __shfl_xor(hn, 1);
    if ((cu & 1) == 0) {
      const unsigned tagw = (unsigned)(((t + 1) >> 1) & 1);
      u64 word = packw(hn, hp, tagw);
      __hip_atomic_store(gex + ((t + 1) & 1) * 2048 + cb * 128 + wg * 8 + (cu >> 1),
                         word, __ATOMIC_RELAXED, __HIP_MEMORY_SCOPE_AGENT);
      // own columns of the h planes for step t+1 (no global round trip);
      // ordered against the next MFMA reads by the next SYNC1.
      const int co = (wg * 8 + (cu >> 1)) * 2;
      *(unsigned*)&hh_lds[cb * 264 + co] = (unsigned)word;
      *(unsigned*)&hl_lds[cb * 264 + co] = (unsigned)(word >> 32);
      *(float2*)(out + ((long)(g * 16 + cb) * S_ + t) * H_ + wg * UPW + cu) =
          make_float2(hn, hp);
    }

    // 5. pre-blast next step's words (returns after ~RT; checked at step t+1)
    if (!own) {
      u64* bsrc = gex + ((t + 1) & 1) * 2048;
      #pragma unroll
      for (int k = 0; k < 8; ++k)
        hv[k] = __hip_atomic_load(bsrc + (k << 8) + tid, __ATOMIC_RELAXED,
                                  __HIP_MEMORY_SCOPE_AGENT);
    }
    zxv = zxn;
  }
}

// ===================== legacy fallback (small-workspace) path =====================

__global__ void pack_h0_kernel(const float* __restrict__ h0, u64* __restrict__ hex) {
  int idx = blockIdx.x * 256 + threadIdx.x;       // 0..4095
  float v0 = h0[idx * 2], v1 = h0[idx * 2 + 1];
  hex[idx] = packw(v0, v1, 0u);
}

__global__ __launch_bounds__(NT, 1) void lstm_persist_fb(
    const float* __restrict__ x, const float* __restrict__ c0,
    const float* __restrict__ W, const float* __restrict__ bias,
    float* __restrict__ out, u64* __restrict__ hex) {

  __shared__ unsigned short hh_lds[32 * 264];
  __shared__ unsigned short hl_lds[32 * 264];
  __shared__ float zbuf[32 * 68];
  __shared__ unsigned short xlds[32 * 264];

  const int tid  = threadIdx.x;
  const int wg   = blockIdx.x;
  const int lane = tid & 63;
  const int wv   = tid >> 6;
  const int mt   = wv & 1;
  const int ct0  = (wv >> 1) * 2;
  const int q    = lane >> 4;
  const int mm   = lane & 15;

  short8 whh[2][8], whl[2][8], wx[2][8];
  float  bia[2];
  #pragma unroll
  for (int c = 0; c < 2; ++c) {
    const int col = (ct0 + c) * 256 + wg * UPW + mm;
    #pragma unroll
    for (int kc = 0; kc < 8; ++kc) {
      short8 vhh, vhl, vx;
      #pragma unroll
      for (int j = 0; j < 8; ++j) {
        int k = kc * 32 + q * 8 + j;
        float whv = W[(long)(256 + k) * 1024 + col];
        unsigned short hh = f2bf(whv);
        vhh[j] = (short)hh;
        vhl[j] = (short)f2bf(whv - bf2f(hh));
        vx[j] = (short)f2bf(W[(long)k * 1024 + col]);
      }
      whh[c][kc] = vhh; whl[c][kc] = vhl; wx[c][kc] = vx;
    }
    bia[c] = bias[(ct0 + c) * 256 + wg * UPW + mm];
  }

  const int cb  = tid >> 3;
  const int cu0 = (tid & 7) * 2;
  float cst[2];
  cst[0] = c0[cb * 256 + wg * UPW + cu0];
  cst[1] = c0[cb * 256 + wg * UPW + cu0 + 1];

  u64* const hex0 = hex;
  u64* const hex1 = hex + 4096;

  for (int t = 0; t < S_; ++t) {
    u64* const hsrc8 = (t & 1) ? hex1 : hex0;
    u64* const hdst8 = (t & 1) ? hex0 : hex1;
    const unsigned tagbit = (unsigned)((t >> 1) & 1);

    u64 hv[16];
    #pragma unroll
    for (int k = 0; k < 16; ++k)
      hv[k] = __hip_atomic_load(hsrc8 + (k << 8) + tid, __ATOMIC_RELAXED,
                                __HIP_MEMORY_SCOPE_AGENT);
    unsigned need = 0;
    #pragma unroll
    for (int k = 0; k < 16; ++k)
      if (((unsigned)(hv[k] >> 32) & 1u) != tagbit) need |= 1u << k;
    while (__ballot(need != 0u) != 0ull) {
      u64 tmp[16];
      #pragma unroll
      for (int k = 0; k < 16; ++k)
        if (need & (1u << k))
          tmp[k] = __hip_atomic_load(hsrc8 + (k << 8) + tid, __ATOMIC_RELAXED,
                                     __HIP_MEMORY_SCOPE_AGENT);
      #pragma unroll
      for (int k = 0; k < 16; ++k)
        if ((need & (1u << k)) && (((unsigned)(tmp[k] >> 32) & 1u) == tagbit)) {
          hv[k] = tmp[k];
          need &= ~(1u << k);
        }
    }

    #pragma unroll
    for (int k = 0; k < 16; ++k) {
      int b  = k * 2 + (tid >> 7);
      int du = (tid & 127);
      *(unsigned*)&hh_lds[b * 264 + du * 2] = (unsigned)hv[k];
      *(unsigned*)&hl_lds[b * 264 + du * 2] = (unsigned)(hv[k] >> 32);
    }
    {
      const int xb = tid >> 3, xi0 = (tid & 7) * 32;
      const float* xp = x + ((long)xb * S_ + t) * I_ + xi0;
      #pragma unroll
      for (int k2 = 0; k2 < 4; ++k2) {
        f32x4 a  = *(const f32x4*)(xp + k2 * 8);
        f32x4 b2 = *(const f32x4*)(xp + k2 * 8 + 4);
        unsigned short u8[8];
        #pragma unroll
        for (int j = 0; j < 4; ++j) { u8[j] = f2bf(a[j]); u8[4 + j] = f2bf(b2[j]); }
        *(uint4*)&xlds[xb * 264 + xi0 + k2 * 8] = *(const uint4*)u8;
      }
    }
    __syncthreads();

    f32x4 accH[2], accM[2], accX[2];
    #pragma unroll
    for (int c = 0; c < 2; ++c) {
      accH[c] = (f32x4){0.f, 0.f, 0.f, 0.f};
      accM[c] = (f32x4){0.f, 0.f, 0.f, 0.f};
      accX[c] = (f32x4){0.f, 0.f, 0.f, 0.f};
    }
    const int arow = mm + 16 * mt;
    #pragma unroll
    for (int kc = 0; kc < 8; ++kc) {
      short8 ahh = *(const short8*)&hh_lds[arow * 264 + kc * 32 + q * 8];
      short8 ahl = *(const short8*)&hl_lds[arow * 264 + kc * 32 + q * 8];
      short8 ax  = *(const short8*)&xlds[arow * 264 + kc * 32 + q * 8];
      #pragma unroll
      for (int c = 0; c < 2; ++c) {
        accH[c] = __builtin_amdgcn_mfma_f32_16x16x32_bf16(ahh, whh[c][kc], accH[c], 0, 0, 0);
        accM[c] = __builtin_amdgcn_mfma_f32_16x16x32_bf16(ahh, whl[c][kc], accM[c], 0, 0, 0);
        accM[c] = __builtin_amdgcn_mfma_f32_16x16x32_bf16(ahl, whh[c][kc], accM[c], 0, 0, 0);
        accX[c] = __builtin_amdgcn_mfma_f32_16x16x32_bf16(ax, wx[c][kc], accX[c], 0, 0, 0);
      }
    }
    #pragma unroll
    for (int c = 0; c < 2; ++c) {
      #pragma unroll
      for (int r = 0; r < 4; ++r) {
        float zp = accH[c][r] + accM[c][r] + accX[c][r] + bia[c];
        int brow = q * 4 + r + 16 * mt;
        zbuf[brow * 68 + (ct0 + c) * 16 + mm] = fast_tanh(zp);
      }
    }
    __syncthreads();

    float hn2[2];
    #pragma unroll
    for (int j = 0; j < 2; ++j) {
      int u = cu0 + j;
      float zi = zbuf[cb * 68 +  0 + u];
      float zf = zbuf[cb * 68 + 16 + u];
      float zg = zbuf[cb * 68 + 32 + u];
      float zo = zbuf[cb * 68 + 48 + u];
      float ig = fast_sig(zi);
      float fg = fast_sig(zf);
      float gg = fast_tanh(zg);
      float og = fast_sig(zo);
      float cn = fg * cst[j] + ig * gg;
      cst[j] = cn;
      hn2[j] = fast_tanh(cn) * og;
    }
    *(float2*)(out + ((long)cb * S_ + t) * H_ + wg * UPW + cu0) =
        make_float2(hn2[0], hn2[1]);
    {
      const unsigned tagw = (unsigned)(((t + 1) >> 1) & 1);
      u64 word = packw(hn2[0], hn2[1], tagw);
      __hip_atomic_store(hdst8 + cb * 128 + wg * 8 + (cu0 >> 1), word,
                         __ATOMIC_RELAXED, __HIP_MEMORY_SCOPE_AGENT);
    }
  }
}

extern "C" void kernel_launch(void* const* d_in, const int* in_sizes, int n_in,
                              void* d_out, int out_size, void* d_ws, size_t ws_size,
                              hipStream_t stream) {
  const float* x    = (const float*)d_in[0];
  const float* h0   = (const float*)d_in[1];
  const float* c0   = (const float*)d_in[2];
  const float* W    = (const float*)d_in[3];
  const float* bias = (const float*)d_in[4];
  float* out = (float*)d_out;

  // ws layout: [0, 64K) h exchange, [64K, 64K+256M) zx
  u64*   hex = (u64*)d_ws;
  float* zx  = (float*)((char*)d_ws + 65536);
  const size_t zx_bytes = (size_t)S_ * B_ * 4 * H_ * sizeof(float);  // 256 MiB

  // outputs 1 and 2 of the reference are zeros
  hipMemsetAsync((char*)d_out + (size_t)B_ * S_ * H_ * 4, 0, 2 * B_ * H_ * 4, stream);

  if (ws_size >= 65536 + zx_bytes) {
    // exchange: [G0p0 16K][G0p1 16K][G1p0 16K][G1p1 16K]; parity-1 buffers
    // start all-ones -> tag bit 1, invalid for their first consumers (t=1)
    hipMemsetAsync((char*)d_ws + 16384, 0xFF, 16384, stream);
    hipMemsetAsync((char*)d_ws + 49152, 0xFF, 16384, stream);
    pack_h0_2grp<<<16, 256, 0, stream>>>(h0, hex);
    zx_precompute2<<<(S_ / TC) * 16, NT, 0, stream>>>(x, W, bias, zx);
    lstm_split<<<32, NT, 0, stream>>>(h0, c0, out, hex, W, zx);
  } else {
    hipMemsetAsync((char*)d_ws + 32768, 0xFF, 32768, stream);
    pack_h0_kernel<<<16, 256, 0, stream>>>(h0, hex);
    lstm_persist_fb<<<16, NT, 0, stream>>>(x, c0, W, bias, out, hex);
  }
}